// Round 1
// baseline (14.005 us; speedup 1.0000x reference)
//
#include <hip/hip_runtime.h>
#include <math.h>

// Problem constants (match reference file)
#define B_ROWS 8192
#define S_COLS 4096
// SIGMA = 1.0, K_FACTOR = 1.0, MARGIN = 0.0

// Kernel 1: one thread per row. 128 blocks x 64 threads = 8192 rows.
// Each block is a single wave -> shuffle reduction, no LDS needed.
// Writes partial[blockIdx]       = sum of loss_i * valid over the 64 rows
//        partial[128+blockIdx]   = sum of valid  (as float; exact for small ints)
__global__ __launch_bounds__(64) void awl_rows_kernel(
    const float* __restrict__ scores,
    const float* __restrict__ labels,
    const float* __restrict__ density,
    const int*   __restrict__ tstar,
    float* __restrict__ partial)
{
    const int row = blockIdx.x * 64 + threadIdx.x;   // always < 8192

    // adaptive half-window: k = ceil(1 / max(density, 0.1))  (k in [2,10])
    const float d  = fmaxf(density[row], 0.1f);
    const int   k  = (int)ceilf(1.0f / d);
    const int   ts = tstar[row];

    const int lo = max(0, ts - k);
    const int hi = min(S_COLS - 1, ts + k);

    const float* __restrict__ srow = scores + (size_t)row * S_COLS;
    const float* __restrict__ lrow = labels + (size_t)row * S_COLS;

    float wsum = 0.0f;          // sum of exp(-dist) over window (>= 1 always)
    float rsum = 0.0f;          // sum of score*exp(-dist) over label==1
    float dsum = 0.0f;          // sum of score*exp(-dist) over label==0
    int   rcnt = 0, dcnt = 0;

    #pragma unroll 4
    for (int t = lo; t <= hi; ++t) {
        const int   dist = (t >= ts) ? (t - ts) : (ts - t);
        const float w    = expf(-(float)dist);
        const float s    = srow[t];
        const float lab  = lrow[t];
        wsum += w;
        const bool isref = (lab == 1.0f);
        if (isref) { rsum += s * w; rcnt++; }
        else       { dsum += s * w; dcnt++; }   // labels are exactly 0.0 or 1.0
    }

    float loss = 0.0f, validf = 0.0f;
    if (rcnt > 0 && dcnt > 0) {
        const float ref_avg = rsum / wsum / (float)rcnt;
        const float dev_avg = dsum / wsum / (float)dcnt;
        const float x = ref_avg - dev_avg;              // + MARGIN(=0)
        // -log_sigmoid(x) = softplus(-x), numerically stable form
        loss   = fmaxf(-x, 0.0f) + log1pf(expf(-fabsf(x)));
        validf = 1.0f;
    }

    // single-wave butterfly reduction (deterministic)
    #pragma unroll
    for (int off = 32; off > 0; off >>= 1) {
        loss   += __shfl_down(loss,   off, 64);
        validf += __shfl_down(validf, off, 64);
    }
    if (threadIdx.x == 0) {
        partial[blockIdx.x]       = loss;
        partial[128 + blockIdx.x] = validf;
    }
}

// Kernel 2: single 64-thread wave reduces the 128 partials deterministically.
__global__ __launch_bounds__(64) void awl_final_kernel(
    const float* __restrict__ partial,
    float* __restrict__ out)
{
    const int tid = threadIdx.x;
    float l = partial[tid]       + partial[tid + 64];
    float c = partial[128 + tid] + partial[128 + tid + 64];
    #pragma unroll
    for (int off = 32; off > 0; off >>= 1) {
        l += __shfl_down(l, off, 64);
        c += __shfl_down(c, off, 64);
    }
    if (tid == 0) {
        out[0] = (c > 0.0f) ? (l / fmaxf(c, 1.0f)) : 0.0f;
    }
}

extern "C" void kernel_launch(void* const* d_in, const int* in_sizes, int n_in,
                              void* d_out, int out_size, void* d_ws, size_t ws_size,
                              hipStream_t stream)
{
    const float* scores  = (const float*)d_in[0];  // [B,S] f32
    const float* labels  = (const float*)d_in[1];  // [B,S] f32 (0/1)
    const float* density = (const float*)d_in[2];  // [B]   f32
    const int*   tstar   = (const int*)  d_in[3];  // [B]   i32
    float*       out     = (float*)d_out;          // scalar f32
    float*       partial = (float*)d_ws;           // 256 floats used

    awl_rows_kernel<<<B_ROWS / 64, 64, 0, stream>>>(scores, labels, density, tstar, partial);
    awl_final_kernel<<<1, 64, 0, stream>>>(partial, out);
}

// Round 2
// 10.932 us; speedup vs baseline: 1.2811x; 1.2811x over previous
//
#include <hip/hip_runtime.h>
#include <math.h>

// Problem constants (match reference file)
#define B_ROWS 8192
#define S_COLS 4096
// SIGMA = 1.0, K_FACTOR = 1.0, MARGIN = 0.0
//
// k = ceil(K_FACTOR / clamp(density, 0.1, inf)) with density ~ U[0,1):
//   1/d > 1 strictly, clamped at 0.1 -> k in [2, 10]. Window half-width <= 10,
//   so offsets o in [-10, 10] cover every possible window: 21 iterations,
//   compile-time constant trip count.

// exp(-|o|) as f32 constants (SIGMA = 1): index by |o|.
__device__ __constant__ const float EXPW[11] = {
    1.0f,            0.36787944f,     0.13533528f,    0.049787068f,
    0.018315639f,    0.0067379470f,   0.0024787522f,  0.00091188197f,
    0.00033546262f,  0.00012340980f,  0.000045399930f
};

// Kernel 1: one thread per row. 128 blocks x 64 threads = 8192 rows.
// Fixed 21-wide window, fully unrolled: all 42 gathered loads go into the
// vmcnt queue together -> one HBM latency, not six.
__global__ __launch_bounds__(64) void awl_rows_kernel(
    const float* __restrict__ scores,
    const float* __restrict__ labels,
    const float* __restrict__ density,
    const int*   __restrict__ tstar,
    float* __restrict__ partial)
{
    const int row = blockIdx.x * 64 + threadIdx.x;   // always < 8192

    const float d  = fmaxf(density[row], 0.1f);
    const int   k  = (int)ceilf(1.0f / d);           // in [2,10]
    const int   ts = tstar[row];

    const float* __restrict__ srow = scores + (size_t)row * S_COLS;
    const float* __restrict__ lrow = labels + (size_t)row * S_COLS;

    // Issue all loads up front (clamped addresses are always in-bounds;
    // out-of-window lanes are masked in the compute pass).
    float s_v[21], l_v[21];
    #pragma unroll
    for (int i = 0; i < 21; ++i) {
        const int t  = ts + (i - 10);
        const int tc = min(max(t, 0), S_COLS - 1);
        s_v[i] = srow[tc];
        l_v[i] = lrow[tc];
    }

    float wsum = 0.0f, rsum = 0.0f, dsum = 0.0f;
    int   rcnt = 0, dcnt = 0;

    #pragma unroll
    for (int i = 0; i < 21; ++i) {
        const int o    = i - 10;
        const int dist = (o < 0) ? -o : o;           // compile-time constant
        const float w  = EXPW[dist];                 // compile-time constant
        const int t    = ts + o;
        const bool in  = (dist <= k) & (t >= 0) & (t < S_COLS);
        if (in) {
            wsum += w;
            const float sw = s_v[i] * w;
            if (l_v[i] == 1.0f) { rsum += sw; rcnt++; }
            else                { dsum += sw; dcnt++; }
        }
    }

    float loss = 0.0f, validf = 0.0f;
    if (rcnt > 0 && dcnt > 0) {
        const float ref_avg = rsum / wsum / (float)rcnt;
        const float dev_avg = dsum / wsum / (float)dcnt;
        const float x = ref_avg - dev_avg;              // + MARGIN(=0)
        // -log_sigmoid(x) = softplus(-x), numerically stable
        loss   = fmaxf(-x, 0.0f) + log1pf(expf(-fabsf(x)));
        validf = 1.0f;
    }

    // single-wave butterfly reduction (deterministic)
    #pragma unroll
    for (int off = 32; off > 0; off >>= 1) {
        loss   += __shfl_down(loss,   off, 64);
        validf += __shfl_down(validf, off, 64);
    }
    if (threadIdx.x == 0) {
        partial[blockIdx.x]       = loss;
        partial[128 + blockIdx.x] = validf;
    }
}

// Kernel 2: single 64-thread wave reduces the 128 partials deterministically.
__global__ __launch_bounds__(64) void awl_final_kernel(
    const float* __restrict__ partial,
    float* __restrict__ out)
{
    const int tid = threadIdx.x;
    float l = partial[tid]       + partial[tid + 64];
    float c = partial[128 + tid] + partial[128 + tid + 64];
    #pragma unroll
    for (int off = 32; off > 0; off >>= 1) {
        l += __shfl_down(l, off, 64);
        c += __shfl_down(c, off, 64);
    }
    if (tid == 0) {
        out[0] = (c > 0.0f) ? (l / fmaxf(c, 1.0f)) : 0.0f;
    }
}

extern "C" void kernel_launch(void* const* d_in, const int* in_sizes, int n_in,
                              void* d_out, int out_size, void* d_ws, size_t ws_size,
                              hipStream_t stream)
{
    const float* scores  = (const float*)d_in[0];  // [B,S] f32
    const float* labels  = (const float*)d_in[1];  // [B,S] f32 (0/1)
    const float* density = (const float*)d_in[2];  // [B]   f32
    const int*   tstar   = (const int*)  d_in[3];  // [B]   i32
    float*       out     = (float*)d_out;          // scalar f32
    float*       partial = (float*)d_ws;           // 256 floats used

    awl_rows_kernel<<<B_ROWS / 64, 64, 0, stream>>>(scores, labels, density, tstar, partial);
    awl_final_kernel<<<1, 64, 0, stream>>>(partial, out);
}